// Round 1
// baseline (1274.013 us; speedup 1.0000x reference)
//
#include <hip/hip_runtime.h>
#include <cstddef>
#include <cstdint>

#define T_ 12
#define H_ 64
#define CIN_ 16
#define F_ 768          // H*T
#define PAD_ROW 772     // 768 + 4 pad: breaks s*768 bank aliasing
#define BN_EPS 1e-5f

// ---------------- CSR build ----------------

__global__ void k_init(int* __restrict__ cnt, int* __restrict__ cursor, int n) {
    int i = blockIdx.x * 256 + threadIdx.x;
    if (i < n) { cnt[i] = 0; cursor[i] = 0; }
}

__global__ void k_count(const int* __restrict__ dstv, int* __restrict__ cnt, int e) {
    int i = blockIdx.x * 256 + threadIdx.x;
    if (i < e) atomicAdd(&cnt[dstv[i]], 1);
}

__global__ void k_dinv(const int* __restrict__ cnt, float* __restrict__ dinv, int n) {
    int i = blockIdx.x * 256 + threadIdx.x;
    if (i < n) dinv[i] = rsqrtf((float)(cnt[i] + 1));   // +1 self loop
}

__global__ void k_scan(const int* __restrict__ cnt, int* __restrict__ row_start, int n) {
    __shared__ int sd[1024];
    __shared__ int carry_s;
    if (threadIdx.x == 0) { carry_s = 0; row_start[0] = 0; }
    __syncthreads();
    for (int base = 0; base < n; base += 1024) {
        int i = base + (int)threadIdx.x;
        int v = (i < n) ? cnt[i] : 0;
        sd[threadIdx.x] = v;
        __syncthreads();
        for (int off = 1; off < 1024; off <<= 1) {
            int t = (threadIdx.x >= (unsigned)off) ? sd[threadIdx.x - off] : 0;
            __syncthreads();
            sd[threadIdx.x] += t;
            __syncthreads();
        }
        int carry = carry_s;
        if (i < n) row_start[i + 1] = carry + sd[threadIdx.x];
        __syncthreads();
        if (threadIdx.x == 1023) carry_s = carry + sd[1023];
        __syncthreads();
    }
}

__global__ void k_scatter(const int* __restrict__ srcv, const int* __restrict__ dstv,
                          const int* __restrict__ row_start, int* __restrict__ cursor,
                          const float* __restrict__ dinv, int* __restrict__ csr_src,
                          float* __restrict__ csr_coef, int e) {
    int i = blockIdx.x * 256 + threadIdx.x;
    if (i < e) {
        int d = dstv[i], s = srcv[i];
        int pos = atomicAdd(&cursor[d], 1);
        int idx = row_start[d] + pos;
        csr_src[idx]  = s;
        csr_coef[idx] = dinv[s] * dinv[d];
    }
}

// ---------------- embedding: xst[n, t*64+h] = relu(x[n,t,:] @ We + be) ----------------
// thread <-> (nt, h4); 16 nt-rows per 256-thread block; x row held in regs, We b128 from LDS.

__global__ __launch_bounds__(256) void k_embed(const float* __restrict__ x,
                                               const float* __restrict__ We,
                                               const float* __restrict__ be,
                                               float* __restrict__ xst, int nT) {
    __shared__ float sW[CIN_ * H_];  // [c*64+h]
    __shared__ float sb[H_];
    for (int i = threadIdx.x; i < CIN_ * H_; i += 256) sW[i] = We[i];
    if (threadIdx.x < H_) sb[threadIdx.x] = be[threadIdx.x];
    __syncthreads();
    int h4  = threadIdx.x & 15;
    int ntl = threadIdx.x >> 4;
    int nt  = blockIdx.x * 16 + ntl;
    if (nt >= nT) return;
    const float4* xp = (const float4*)(x + (size_t)nt * CIN_);
    float4 xv4[4];
    xv4[0] = xp[0]; xv4[1] = xp[1]; xv4[2] = xp[2]; xv4[3] = xp[3];
    const float* xs = (const float*)xv4;
    float acc[4];
#pragma unroll
    for (int j = 0; j < 4; j++) acc[j] = sb[h4 * 4 + j];
#pragma unroll
    for (int c = 0; c < CIN_; c++) {
        float4 w = *(const float4*)&sW[c * H_ + h4 * 4];
        float xc = xs[c];
        acc[0] += xc * w.x; acc[1] += xc * w.y; acc[2] += xc * w.z; acc[3] += xc * w.w;
    }
    float4 o;
    o.x = fmaxf(acc[0], 0.f); o.y = fmaxf(acc[1], 0.f);
    o.z = fmaxf(acc[2], 0.f); o.w = fmaxf(acc[3], 0.f);
    *(float4*)&xst[(size_t)nt * H_ + h4 * 4] = o;
}

// ---------------- GCN linear: h[n, d*12+t] = sum_c xst[n, c*12+t] * W[c,d] ----------------
// 8 nodes/block, 128 threads, thread <-> (s, d4): acc[4][12].

__global__ __launch_bounds__(128) void k_lin(const float* __restrict__ xst,
                                             const float* __restrict__ W,
                                             float* __restrict__ hb, int n) {
    __shared__ float sx[8 * PAD_ROW];   // [s][c*12+t]
    __shared__ float sW[H_ * H_];       // [c*64+d]
    int tid = threadIdx.x;
    for (int i = tid; i < H_ * H_; i += 128) sW[i] = W[i];
    int n0 = blockIdx.x * 8;
    for (int i = tid; i < 8 * F_; i += 128) {
        int s = i / F_, j = i - s * F_;
        int nn = n0 + s; if (nn >= n) nn = n - 1;
        sx[s * PAD_ROW + j] = xst[(size_t)nn * F_ + j];
    }
    __syncthreads();
    int s = tid >> 4, d4 = tid & 15;
    float acc[4][12];
#pragma unroll
    for (int j = 0; j < 4; j++)
#pragma unroll
        for (int t = 0; t < 12; t++) acc[j][t] = 0.f;
    const float* xr = &sx[s * PAD_ROW];
    for (int c = 0; c < H_; c++) {
        float4 q0 = *(const float4*)&xr[c * 12];
        float4 q1 = *(const float4*)&xr[c * 12 + 4];
        float4 q2 = *(const float4*)&xr[c * 12 + 8];
        float xv[12] = {q0.x, q0.y, q0.z, q0.w, q1.x, q1.y, q1.z, q1.w, q2.x, q2.y, q2.z, q2.w};
        float4 w = *(const float4*)&sW[c * H_ + d4 * 4];
#pragma unroll
        for (int t = 0; t < 12; t++) {
            acc[0][t] += w.x * xv[t]; acc[1][t] += w.y * xv[t];
            acc[2][t] += w.z * xv[t]; acc[3][t] += w.w * xv[t];
        }
    }
    int nn = n0 + s;
    if (nn < n) {
        float* hp = hb + (size_t)nn * F_ + d4 * 48;
#pragma unroll
        for (int j = 0; j < 4; j++)
#pragma unroll
            for (int q = 0; q < 3; q++) {
                float4 o;
                o.x = acc[j][q * 4 + 0]; o.y = acc[j][q * 4 + 1];
                o.z = acc[j][q * 4 + 2]; o.w = acc[j][q * 4 + 3];
                *(float4*)&hp[j * 12 + q * 4] = o;
            }
    }
}

// ---------------- aggregate: agg[n,f] = selfcoef*h[n,f] + sum_e coef*h[src,f] + gcn_b[f/12] ----

__global__ __launch_bounds__(256) void k_agg(const float* __restrict__ hb,
                                             const int* __restrict__ row_start,
                                             const int* __restrict__ csr_src,
                                             const float* __restrict__ csr_coef,
                                             const float* __restrict__ dinv,
                                             const float* __restrict__ gb,
                                             float* __restrict__ agg, int n) {
    int nn = blockIdx.x;
    int tid = threadIdx.x;
    float a0, a1, a2;
    {
        float dn = dinv[nn];
        float cs = dn * dn;
        const float* hp = hb + (size_t)nn * F_;
        a0 = cs * hp[tid]; a1 = cs * hp[tid + 256]; a2 = cs * hp[tid + 512];
    }
    int beg = row_start[nn], end = row_start[nn + 1];
    for (int e = beg; e < end; e++) {
        int sidx = csr_src[e];
        float c = csr_coef[e];
        const float* hp = hb + (size_t)sidx * F_;
        a0 += c * hp[tid]; a1 += c * hp[tid + 256]; a2 += c * hp[tid + 512];
    }
    float* ap = agg + (size_t)nn * F_;
    ap[tid]       = a0 + gb[tid / 12];
    ap[tid + 256] = a1 + gb[(tid + 256) / 12];
    ap[tid + 512] = a2 + gb[(tid + 512) / 12];
}

// ---------------- temporal conv(k=3,pad=1) + BN + residual + ReLU, in-place on xst ----------
// 8 nodes/block, 128 threads, thread <-> (s, o4): acc[4][12]; one k-plane of w in LDS at a time.

__global__ __launch_bounds__(128) void k_conv(const float* __restrict__ agg,
                                              const float* __restrict__ cw,
                                              const float* __restrict__ cb,
                                              const float* __restrict__ bng,
                                              const float* __restrict__ bnb,
                                              const float* __restrict__ bnm,
                                              const float* __restrict__ bnv,
                                              float* __restrict__ xst, int n) {
    __shared__ float sa[8 * PAD_ROW];   // [s][c*12+t]
    __shared__ float sw[64 * 65];       // one k-plane, [c*65+o]
    int tid = threadIdx.x;
    int n0 = blockIdx.x * 8;
    for (int i = tid; i < 8 * F_; i += 128) {
        int s = i / F_, j = i - s * F_;
        int nn = n0 + s; if (nn >= n) nn = n - 1;
        sa[s * PAD_ROW + j] = agg[(size_t)nn * F_ + j];
    }
    int s = tid >> 4, o4 = tid & 15;
    float acc[4][12];
#pragma unroll
    for (int j = 0; j < 4; j++)
#pragma unroll
        for (int t = 0; t < 12; t++) acc[j][t] = 0.f;
#pragma unroll
    for (int k = 0; k < 3; k++) {
        __syncthreads();
        for (int i = tid; i < 4096; i += 128) {
            int o = i >> 6, c = i & 63;
            sw[c * 65 + o] = cw[(size_t)(o * 64 + c) * 3 + k];
        }
        __syncthreads();
        const float* xbase = &sa[s * PAD_ROW];
        for (int c = 0; c < 64; c++) {
            const float* xr = xbase + c * 12;
            float4 q0 = *(const float4*)(xr);
            float4 q1 = *(const float4*)(xr + 4);
            float4 q2 = *(const float4*)(xr + 8);
            float xv[12] = {q0.x, q0.y, q0.z, q0.w, q1.x, q1.y, q1.z, q1.w, q2.x, q2.y, q2.z, q2.w};
            const float* wr = &sw[c * 65 + o4 * 4];
            float w0 = wr[0], w1 = wr[1], w2 = wr[2], w3 = wr[3];
#pragma unroll
            for (int t = 0; t < 12; t++) {
                int tt = t + k - 1;
                if (tt >= 0 && tt < 12) {
                    float xc = xv[tt];
                    acc[0][t] += w0 * xc; acc[1][t] += w1 * xc;
                    acc[2][t] += w2 * xc; acc[3][t] += w3 * xc;
                }
            }
        }
    }
    int nn = n0 + s;
    if (nn < n) {
        float* xp = xst + (size_t)nn * F_;
#pragma unroll
        for (int j = 0; j < 4; j++) {
            int o = o4 * 4 + j;
            float scale = bng[o] * rsqrtf(bnv[o] + BN_EPS);
            float shift = bnb[o] - bnm[o] * scale;
            float cbo = cb[o];
#pragma unroll
            for (int q = 0; q < 3; q++) {
                float4 r = *(const float4*)&xp[o * 12 + q * 4];
                float4 w;
                w.x = fmaxf((acc[j][q * 4 + 0] + cbo) * scale + shift + r.x, 0.f);
                w.y = fmaxf((acc[j][q * 4 + 1] + cbo) * scale + shift + r.y, 0.f);
                w.z = fmaxf((acc[j][q * 4 + 2] + cbo) * scale + shift + r.z, 0.f);
                w.w = fmaxf((acc[j][q * 4 + 3] + cbo) * scale + shift + r.w, 0.f);
                *(float4*)&xp[o * 12 + q * 4] = w;
            }
        }
    }
}

// ---------------- dual attention + output MLP ----------------
// 8 nodes/block, 128 threads. Rows transposed in LDS: sT[s][h*12+t].

__global__ __launch_bounds__(128) void k_attn(const float* __restrict__ xst,
        const float* __restrict__ taw1, const float* __restrict__ tab1,
        const float* __restrict__ taw2, const float* __restrict__ tab2,
        const float* __restrict__ faw1, const float* __restrict__ fab1,
        const float* __restrict__ faw2, const float* __restrict__ fab2,
        const float* __restrict__ ow1, const float* __restrict__ ob1,
        const float* __restrict__ ow2, const float* __restrict__ ob2,
        float* __restrict__ out, int n) {
    __shared__ float sT[8 * PAD_ROW];       // [s][h*12+t]
    __shared__ float s_taw1[2048];          // [h*32+m]
    __shared__ float s_ow1[2048];           // [h*32+m]
    __shared__ float s_tab1[32], s_taw2[32], s_ob1[32], s_ow2[32];
    __shared__ float s_faw1[72], s_fab1[8], s_faw2[8];
    __shared__ float s_tw[8 * 12];
    __shared__ float s_xf[8 * 65];
    int tid = threadIdx.x;
    int n0 = blockIdx.x * 8;
    for (int i = tid; i < 2048; i += 128) { s_taw1[i] = taw1[i]; s_ow1[i] = ow1[i]; }
    if (tid < 32) {
        s_tab1[tid] = tab1[tid]; s_taw2[tid] = taw2[tid];
        s_ob1[tid] = ob1[tid];   s_ow2[tid] = ow2[tid];
    }
    if (tid < 72) s_faw1[tid] = faw1[tid];
    if (tid < 6) { s_fab1[tid] = fab1[tid]; s_faw2[tid] = faw2[tid]; }
    float tb2 = tab2[0], fb2 = fab2[0], o_b2 = ob2[0];
    for (int i = tid; i < 8 * F_; i += 128) {
        int s = i / F_, j = i - s * F_;
        int t = j >> 6, hh = j & 63;
        int nn = n0 + s; if (nn >= n) nn = n - 1;
        sT[s * PAD_ROW + hh * 12 + t] = xst[(size_t)nn * F_ + j];
    }
    __syncthreads();

    int s = tid >> 4, m2 = tid & 15;   // s 0..7, m2 0..15 (2 hidden units each)
    // ---- phase B: temporal-attention MLP hidden + logits ----
    {
        float a0[12], a1[12];
        float b0 = s_tab1[2 * m2], b1 = s_tab1[2 * m2 + 1];
#pragma unroll
        for (int t = 0; t < 12; t++) { a0[t] = b0; a1[t] = b1; }
        const float* xr = &sT[s * PAD_ROW];
        for (int hh = 0; hh < 64; hh++) {
            float4 q0 = *(const float4*)&xr[hh * 12];
            float4 q1 = *(const float4*)&xr[hh * 12 + 4];
            float4 q2 = *(const float4*)&xr[hh * 12 + 8];
            float xv[12] = {q0.x, q0.y, q0.z, q0.w, q1.x, q1.y, q1.z, q1.w, q2.x, q2.y, q2.z, q2.w};
            float w0 = s_taw1[hh * 32 + 2 * m2], w1 = s_taw1[hh * 32 + 2 * m2 + 1];
#pragma unroll
            for (int t = 0; t < 12; t++) { a0[t] += w0 * xv[t]; a1[t] += w1 * xv[t]; }
        }
        float w20 = s_taw2[2 * m2], w21 = s_taw2[2 * m2 + 1];
#pragma unroll
        for (int t = 0; t < 12; t++) {
            float p = fmaxf(a0[t], 0.f) * w20 + fmaxf(a1[t], 0.f) * w21;
            p += __shfl_xor(p, 1); p += __shfl_xor(p, 2);
            p += __shfl_xor(p, 4); p += __shfl_xor(p, 8);
            if (m2 == 0) s_tw[s * 12 + t] = p + tb2;
        }
    }
    __syncthreads();

    // ---- phase C: softmax(tw), xt, feature attention, x_final ----
    int wave = tid >> 6, lane = tid & 63;
    for (int q = 0; q < 4; q++) {
        int ss = wave * 4 + q;
        float tw[12];
#pragma unroll
        for (int t = 0; t < 12; t++) tw[t] = s_tw[ss * 12 + t];
        float mx = tw[0];
#pragma unroll
        for (int t = 1; t < 12; t++) mx = fmaxf(mx, tw[t]);
        float sum = 0.f;
#pragma unroll
        for (int t = 0; t < 12; t++) { tw[t] = __expf(tw[t] - mx); sum += tw[t]; }
        float inv = 1.f / sum;
        const float* xr = &sT[ss * PAD_ROW + lane * 12];
        float4 q0 = *(const float4*)(xr);
        float4 q1 = *(const float4*)(xr + 4);
        float4 q2 = *(const float4*)(xr + 8);
        float xv[12] = {q0.x, q0.y, q0.z, q0.w, q1.x, q1.y, q1.z, q1.w, q2.x, q2.y, q2.z, q2.w};
        float xt[12];
#pragma unroll
        for (int t = 0; t < 12; t++) xt[t] = xv[t] * tw[t] * inv;
        float lf = fb2;
#pragma unroll
        for (int mm = 0; mm < 6; mm++) {
            float v = s_fab1[mm];
#pragma unroll
            for (int t = 0; t < 12; t++) v += xt[t] * s_faw1[t * 6 + mm];
            lf += fmaxf(v, 0.f) * s_faw2[mm];
        }
        float m2v = lf;
#pragma unroll
        for (int off = 32; off >= 1; off >>= 1) m2v = fmaxf(m2v, __shfl_xor(m2v, off));
        float e = __expf(lf - m2v);
        float se = e;
#pragma unroll
        for (int off = 32; off >= 1; off >>= 1) se += __shfl_xor(se, off);
        float fwv = e / se;
        float xs = 0.f;
#pragma unroll
        for (int t = 0; t < 12; t++) xs += xt[t];
        s_xf[ss * 65 + lane] = fwv * xs;
    }
    __syncthreads();

    // ---- phase D: output MLP ----
    {
        float v0 = s_ob1[2 * m2], v1 = s_ob1[2 * m2 + 1];
        const float* xfp = &s_xf[s * 65];
        for (int hh = 0; hh < 64; hh++) {
            float xv = xfp[hh];
            v0 += xv * s_ow1[hh * 32 + 2 * m2];
            v1 += xv * s_ow1[hh * 32 + 2 * m2 + 1];
        }
        float p = fmaxf(v0, 0.f) * s_ow2[2 * m2] + fmaxf(v1, 0.f) * s_ow2[2 * m2 + 1];
        p += __shfl_xor(p, 1); p += __shfl_xor(p, 2);
        p += __shfl_xor(p, 4); p += __shfl_xor(p, 8);
        if (m2 == 0 && n0 + s < n) out[n0 + s] = p + o_b2;
    }
}

// ---------------- launcher ----------------

extern "C" void kernel_launch(void* const* d_in, const int* in_sizes, int n_in,
                              void* d_out, int out_size, void* d_ws, size_t ws_size,
                              hipStream_t stream) {
    const float* x      = (const float*)d_in[0];
    const int*   ei     = (const int*)d_in[1];
    const float* We     = (const float*)d_in[2];
    const float* be     = (const float*)d_in[3];
    const float* gcn_W  = (const float*)d_in[4];
    const float* gcn_b  = (const float*)d_in[5];
    const float* conv_w = (const float*)d_in[6];
    const float* conv_b = (const float*)d_in[7];
    const float* bn_g   = (const float*)d_in[8];
    const float* bn_b   = (const float*)d_in[9];
    const float* bn_m   = (const float*)d_in[10];
    const float* bn_v   = (const float*)d_in[11];
    const float* ta_w1  = (const float*)d_in[12];
    const float* ta_b1  = (const float*)d_in[13];
    const float* ta_w2  = (const float*)d_in[14];
    const float* ta_b2  = (const float*)d_in[15];
    const float* fa_w1  = (const float*)d_in[16];
    const float* fa_b1  = (const float*)d_in[17];
    const float* fa_w2  = (const float*)d_in[18];
    const float* fa_b2  = (const float*)d_in[19];
    const float* ow1    = (const float*)d_in[20];
    const float* ob1    = (const float*)d_in[21];
    const float* ow2    = (const float*)d_in[22];
    const float* ob2    = (const float*)d_in[23];

    int n = in_sizes[0] / (T_ * CIN_);
    int e = in_sizes[1] / 2;
    const int* srcv = ei;
    const int* dstv = ei + e;

    char* p = (char*)d_ws;
    auto take = [&](size_t bytes) -> void* {
        void* r = (void*)p;
        p += (bytes + 255) & ~(size_t)255;
        return r;
    };
    int*   cnt       = (int*)take((size_t)n * 4);
    int*   cursor    = (int*)take((size_t)n * 4);
    int*   row_start = (int*)take(((size_t)n + 1) * 4);
    float* dinv      = (float*)take((size_t)n * 4);
    int*   csr_src   = (int*)take((size_t)e * 4);
    float* csr_coef  = (float*)take((size_t)e * 4);
    float* xst       = (float*)take((size_t)n * F_ * 4);
    float* hbuf      = (float*)take((size_t)n * F_ * 4);
    float* aggbuf    = (float*)take((size_t)n * F_ * 4);

    int nb_n = (n + 255) / 256;
    int nb_e = (e + 255) / 256;

    k_init<<<nb_n, 256, 0, stream>>>(cnt, cursor, n);
    k_count<<<nb_e, 256, 0, stream>>>(dstv, cnt, e);
    k_dinv<<<nb_n, 256, 0, stream>>>(cnt, dinv, n);
    k_scan<<<1, 1024, 0, stream>>>(cnt, row_start, n);
    k_scatter<<<nb_e, 256, 0, stream>>>(srcv, dstv, row_start, cursor, dinv,
                                        csr_src, csr_coef, e);

    int nT = n * T_;
    k_embed<<<(nT + 15) / 16, 256, 0, stream>>>(x, We, be, xst, nT);

    int nb8 = (n + 7) / 8;
    for (int i = 0; i < 3; i++) {
        k_lin<<<nb8, 128, 0, stream>>>(xst, gcn_W + (size_t)i * H_ * H_, hbuf, n);
        k_agg<<<n, 256, 0, stream>>>(hbuf, row_start, csr_src, csr_coef, dinv,
                                     gcn_b + (size_t)i * H_, aggbuf, n);
        k_conv<<<nb8, 128, 0, stream>>>(aggbuf, conv_w + (size_t)i * H_ * H_ * 3,
                                        conv_b + (size_t)i * H_,
                                        bn_g + (size_t)i * H_, bn_b + (size_t)i * H_,
                                        bn_m + (size_t)i * H_, bn_v + (size_t)i * H_,
                                        xst, n);
    }

    k_attn<<<nb8, 128, 0, stream>>>(xst, ta_w1, ta_b1, ta_w2, ta_b2,
                                    fa_w1, fa_b1, fa_w2, fa_b2,
                                    ow1, ob1, ow2, ob2, (float*)d_out, n);
}